// Round 4
// baseline (688.303 us; speedup 1.0000x reference)
//
#include <hip/hip_runtime.h>
#include <hip/hip_bf16.h>
#include <math.h>

// linearGPT2 cell: B=2048 D=1024 H=16 DH=64 R=32. fp32 I/O, bf16 MFMA compute.
// Pipeline: wtrans(W fp32 -> W^T bf16) -> LN1 -> GEMM(qkv) -> attn core
//           -> GEMM(proj) -> LN2(+x) -> GEMM(fc)+GELU -> GEMM(mp,split-K=2)
//           -> reduce(+bias+res) -> out.
// GEMM: T3-lite 2-phase double-buffered LDS. Per K-64 pair: STAGE(next half)
//       issued BEFORE compute of current half; one __syncthreads (vmcnt drain)
//       per 32-K step. Hides global-load latency at 1.5-2 blocks/CU.
// Workspace EXACTLY 64 MB; transposed weights + mp partials alias dead regions.

#define Bsz 2048
#define Dm  1024
#define Hh  16
#define DHd 64
#define Rr  32

typedef __bf16 bf16x8 __attribute__((ext_vector_type(8)));
typedef __bf16 bf16x4 __attribute__((ext_vector_type(4)));
typedef float  f32x4  __attribute__((ext_vector_type(4)));

__device__ __forceinline__ __bf16 f2bf(float x) { return (__bf16)x; }

// async global->LDS, 16B per lane, LDS dst = wave-uniform base + lane*16
#define GLOAD_LDS16(g, l) __builtin_amdgcn_global_load_lds(               \
    (const __attribute__((address_space(1))) void*)(g),                   \
    (__attribute__((address_space(3))) void*)(l), 16, 0, 0)

// ---------------- weight transpose + convert: W[K][N] f32 -> Wt[N][K] bf16 --
__global__ __launch_bounds__(256) void wtrans_kernel(
    const float* __restrict__ W, __bf16* __restrict__ Wt, int K, int N)
{
  __shared__ float tile[32][33];
  const int tx = threadIdx.x & 31;
  const int ty0 = threadIdx.x >> 5;      // 0..7
  const int bn = blockIdx.x * 32;
  const int bk = blockIdx.y * 32;
#pragma unroll
  for (int j = 0; j < 4; ++j)
    tile[ty0 + j * 8][tx] = W[(size_t)(bk + ty0 + j * 8) * N + bn + tx];
  __syncthreads();
#pragma unroll
  for (int j = 0; j < 4; ++j) {
    const int ny = ty0 + j * 8;
    Wt[(size_t)(bn + ny) * K + bk + tx] = f2bf(tile[tx][ny]);
  }
}

// ---------------- LayerNorm (optionally fused residual add + fp32 copy) ----
template<bool ADD, typename TA>
__global__ __launch_bounds__(256) void ln_kernel(
    const TA* __restrict__ a, const float* __restrict__ b2,
    const float* __restrict__ g, const float* __restrict__ beta,
    __bf16* __restrict__ outb, float* __restrict__ outf)
{
  const int row = blockIdx.x;
  const int t = threadIdx.x;
  const size_t base = (size_t)row * Dm;
  float vals[4];
#pragma unroll
  for (int i = 0; i < 4; ++i) {
    const int c = t * 4 + i;
    float v = (float)a[base + c];
    if (ADD) v += b2[base + c];
    vals[i] = v;
  }
  float sm = 0.f, sq = 0.f;
#pragma unroll
  for (int i = 0; i < 4; ++i) { sm += vals[i]; sq += vals[i] * vals[i]; }
  for (int off = 32; off > 0; off >>= 1) {
    sm += __shfl_down(sm, off);
    sq += __shfl_down(sq, off);
  }
  __shared__ float smw[4], sqw[4];
  if ((t & 63) == 0) { smw[t >> 6] = sm; sqw[t >> 6] = sq; }
  __syncthreads();
  const float S  = smw[0] + smw[1] + smw[2] + smw[3];
  const float SS = sqw[0] + sqw[1] + sqw[2] + sqw[3];
  const float mean = S * (1.f / Dm);
  const float var  = SS * (1.f / Dm) - mean * mean;
  const float inv  = rsqrtf(var + 1e-3f);
#pragma unroll
  for (int i = 0; i < 4; ++i) {
    const int c = t * 4 + i;
    const float r = g[c] * ((vals[i] - mean) * inv) + beta[c];
    outb[base + c] = f2bf(r);
    if (ADD) outf[base + c] = r;  // fp32 copy for the final residual
  }
}

// ---------------- bf16 MFMA GEMM: C = A[MxK] @ Wt[NxK]^T + bias ------------
// 256 threads = 4 waves (2x2). Wave tile (BM/2)x(BN/2). BK=32, dbuf 2-phase.
// SPLITK2: blockIdx.z selects K-half; writes raw fp32 partial at Cv + z*M*N.
template<int BM, int BN, bool GELU, bool RES, bool OUTF32, bool SPLITK2>
__global__ __launch_bounds__(256) void gemm_kernel(
    const __bf16* __restrict__ A, const __bf16* __restrict__ Bt,
    const float* __restrict__ bias, const float* __restrict__ res,
    void* __restrict__ Cv, int M, int N, int K)
{
  constexpr int FM = BM / 32;   // m-frags per wave
  constexpr int FN = BN / 32;   // n-frags per wave
  __shared__ __align__(16) __bf16 lsA[2][BM * 32];
  __shared__ __align__(16) __bf16 lsB[2][BN * 32];
  const int t = threadIdx.x;
  const int wave = t >> 6, lane = t & 63;
  const int quad = lane >> 4, l16 = lane & 15;
  const int wm = wave >> 1, wn = wave & 1;
  const int bm = blockIdx.x * BM, bn = blockIdx.y * BN;
  const int kHalf = SPLITK2 ? K / 2 : K;
  const int k0 = SPLITK2 ? blockIdx.z * kHalf : 0;
  const int kEnd = k0 + kHalf;

  const int srow = lane >> 2, scol = (lane & 3) * 8;  // lane -> 16B in 16x32 slab
  const __bf16* Ag = A  + (size_t)(bm + wave * 16 + srow) * K + scol;
  const __bf16* Bg = Bt + (size_t)(bn + wave * 16 + srow) * K + scol;

  f32x4 acc[FM][FN];
#pragma unroll
  for (int mi = 0; mi < FM; ++mi)
#pragma unroll
    for (int ni = 0; ni < FN; ++ni)
      acc[mi][ni] = (f32x4){0.f, 0.f, 0.f, 0.f};

  auto STAGE = [&](int buf, int kt) {
#pragma unroll
    for (int i = 0; i < BM / 64; ++i)
      GLOAD_LDS16(Ag + (size_t)(i * 64) * K + kt,
                  &lsA[buf][(i * 64 + wave * 16) * 32]);
#pragma unroll
    for (int i = 0; i < BN / 64; ++i)
      GLOAD_LDS16(Bg + (size_t)(i * 64) * K + kt,
                  &lsB[buf][(i * 64 + wave * 16) * 32]);
  };
  auto COMPUTE = [&](int buf) {
    bf16x8 af[FM], bfr[FN];
#pragma unroll
    for (int mi = 0; mi < FM; ++mi)
      af[mi] = *(const bf16x8*)
          &lsA[buf][(wm * (BM / 2) + mi * 16 + l16) * 32 + quad * 8];
#pragma unroll
    for (int ni = 0; ni < FN; ++ni)
      bfr[ni] = *(const bf16x8*)
          &lsB[buf][(wn * (BN / 2) + ni * 16 + l16) * 32 + quad * 8];
#pragma unroll
    for (int mi = 0; mi < FM; ++mi)
#pragma unroll
      for (int ni = 0; ni < FN; ++ni)
        acc[mi][ni] = __builtin_amdgcn_mfma_f32_16x16x32_bf16(
            af[mi], bfr[ni], acc[mi][ni], 0, 0, 0);
  };

  // T3-lite 2-phase: stage next half-pair before computing current; one
  // vmcnt(0)+barrier (inside __syncthreads) per 32-K step.
  STAGE(0, k0);
  __syncthreads();
  for (int kt = k0; kt < kEnd - 64; kt += 64) {
    STAGE(1, kt + 32);
    COMPUTE(0);
    __syncthreads();
    STAGE(0, kt + 64);
    COMPUTE(1);
    __syncthreads();
  }
  STAGE(1, kEnd - 32);
  COMPUTE(0);
  __syncthreads();
  COMPUTE(1);

#pragma unroll
  for (int mi = 0; mi < FM; ++mi) {
    const int row0 = bm + wm * (BM / 2) + mi * 16 + quad * 4;
#pragma unroll
    for (int ni = 0; ni < FN; ++ni) {
      const int col = bn + wn * (BN / 2) + ni * 16 + l16;
      const float bv = SPLITK2 ? 0.f : bias[col];
#pragma unroll
      for (int i = 0; i < 4; ++i) {
        const int row = row0 + i;
        float v = acc[mi][ni][i] + bv;
        if (SPLITK2) {
          ((float*)Cv)[(size_t)blockIdx.z * M * N + (size_t)row * N + col] = v;
        } else {
          if (GELU) v = 0.5f * v * (1.0f + erff(v * 0.70710678118654752f));
          if (RES) v += res[(size_t)row * N + col];
          if (OUTF32) ((float*)Cv)[(size_t)row * N + col] = v;
          else        ((__bf16*)Cv)[(size_t)row * N + col] = f2bf(v);
        }
      }
    }
  }
}

// ---------------- split-K reduce: out = p0 + p1 + bias + res ---------------
__global__ __launch_bounds__(256) void reduce_mp_kernel(
    const float* __restrict__ p, const float* __restrict__ bias,
    const float* __restrict__ res, float* __restrict__ out)
{
  const size_t i = ((size_t)blockIdx.x * 256 + threadIdx.x) * 4;
  const f32x4 a = *(const f32x4*)(p + i);
  const f32x4 b = *(const f32x4*)(p + (size_t)Bsz * Dm + i);
  const f32x4 r = *(const f32x4*)(res + i);
  const f32x4 bv = *(const f32x4*)(bias + (i & (Dm - 1)));
  *(f32x4*)(out + i) = a + b + r + bv;
}

// ---------------- fused linear-attention core ------------------------------
// 256 threads = 4 waves, one (b,h) per wave. phi sigmoids, new_s/new_z,
// head=num/den. s/new_s stream vectorized to f32x4 (16B/lane).
__global__ __launch_bounds__(256) void attn_kernel(
    const float* __restrict__ qkv, const float* __restrict__ s,
    const float* __restrict__ z,
    const float* __restrict__ w1, const float* __restrict__ w2,
    const float* __restrict__ w3, const float* __restrict__ w4,
    float* __restrict__ new_s, float* __restrict__ new_z,
    __bf16* __restrict__ head)
{
  const int wave = threadIdx.x >> 6, lane = threadIdx.x & 63;
  const int bh = blockIdx.x * 4 + wave;
  const int b = bh >> 4, h = bh & 15;
  __shared__ float ksh[4][64], qsh[4][64], vsh[4][64];
  __shared__ float phish[4][4][32];
  __shared__ float nzsh[4][32];

  const float* qrow = qkv + (size_t)b * (3 * Dm) + h * 64 + lane;
  qsh[wave][lane] = qrow[0];
  ksh[wave][lane] = qrow[Dm];
  vsh[wave][lane] = qrow[2 * Dm];
  __syncthreads();

  {  // 128 dots of length 64: 2 per thread. w[h,d,r] stride 32 over d.
    const int r = lane & 31;
    for (int it = 0; it < 2; ++it) {
      const int mm = (lane >> 5) + it * 2;            // 0/1 then 2/3
      const float* wp = (mm == 0) ? w1 : (mm == 1) ? w2 : (mm == 2) ? w3 : w4;
      const float* w = wp + (size_t)h * (DHd * Rr) + r;
      const float* src = (it == 0) ? ksh[wave] : qsh[wave];
      float acc = 0.f;
#pragma unroll 8
      for (int d = 0; d < 64; ++d) acc += src[d] * w[(size_t)d * 32];
      phish[wave][mm][r] = 1.f / (1.f + expf(-acc));
    }
  }
  __syncthreads();

  const size_t zbase = (size_t)b * (Rr * Hh) + h * Rr;
  if (lane < 32) {
    const float nz = z[zbase + lane] + phish[wave][1][lane];
    new_z[zbase + lane] = nz;
    nzsh[wave][lane] = nz;
  }
  __syncthreads();

  float den = 0.f;
#pragma unroll
  for (int r = 0; r < 32; ++r) den += phish[wave][3][r] * nzsh[wave][r];

  const size_t sbase = ((size_t)b * Hh + h) * (Rr * DHd);
  const int d4 = (lane & 15) * 4, rr = lane >> 4;
  const f32x4 vv4 = *(const f32x4*)&vsh[wave][d4];
  f32x4 num4 = {0.f, 0.f, 0.f, 0.f};
#pragma unroll
  for (int rb = 0; rb < 8; ++rb) {
    const int r = rb * 4 + rr;
    f32x4 sv = *(const f32x4*)(s + sbase + r * 64 + d4);
    const f32x4 ns = sv + phish[wave][0][r] * vv4;
    *(f32x4*)(new_s + sbase + r * 64 + d4) = ns;
    num4 += phish[wave][2][r] * ns;
  }
#pragma unroll
  for (int i = 0; i < 4; ++i) {
    num4[i] += __shfl_xor(num4[i], 16);
    num4[i] += __shfl_xor(num4[i], 32);
  }
  if (rr == 0) {
    const float inv = 1.f / den;
    bf16x4 hv;
#pragma unroll
    for (int i = 0; i < 4; ++i) hv[i] = f2bf(num4[i] * inv);
    *(bf16x4*)(head + (size_t)b * Dm + h * 64 + d4) = hv;
  }
}

// ---------------------------------------------------------------------------
extern "C" void kernel_launch(void* const* d_in, const int* in_sizes, int n_in,
                              void* d_out, int out_size, void* d_ws, size_t ws_size,
                              hipStream_t stream)
{
  const float* x      = (const float*)d_in[0];
  const float* s_in   = (const float*)d_in[1];
  const float* z_in   = (const float*)d_in[2];
  const float* ln1_g  = (const float*)d_in[3];
  const float* ln1_b  = (const float*)d_in[4];
  const float* ln2_g  = (const float*)d_in[5];
  const float* ln2_b  = (const float*)d_in[6];
  const float* W_attn = (const float*)d_in[7];
  const float* b_attn = (const float*)d_in[8];
  const float* W_proj = (const float*)d_in[9];
  const float* b_proj = (const float*)d_in[10];
  const float* W_fc   = (const float*)d_in[11];
  const float* b_fc   = (const float*)d_in[12];
  const float* W_mp   = (const float*)d_in[13];
  const float* b_mp   = (const float*)d_in[14];
  const float* w1     = (const float*)d_in[15];
  const float* w2     = (const float*)d_in[16];
  const float* w3     = (const float*)d_in[17];
  const float* w4     = (const float*)d_in[18];

  float* out0  = (float*)d_out;                        // [B,D]
  float* out_s = out0 + (size_t)Bsz * Dm;              // [B,D*R]
  float* out_z = out_s + (size_t)Bsz * Dm * Rr;        // [B,R*H]

  // 64 MB workspace layout (offsets in MB):
  //   0: h1(4) | 4: qkv(24) | 28: headp(4) | 32: attnb(4) | 36: h2b(4)
  //  40: h2f(8) | 48: fcb(16)
  // aliases: Wt_attn@48(6) Wt_proj@54(2)  [dead before fcb written]
  //          Wt_fc@4(8)    Wt_mp@12(8)    [written after qkv's last read]
  //          mp_part@20(16)               [qkv tail + headp + attnb, all dead]
  char* ws = (char*)d_ws;
  __bf16* h1    = (__bf16*)(ws);
  float*  qkv   = (float*) (ws + ((size_t)4  << 20));
  __bf16* headp = (__bf16*)(ws + ((size_t)28 << 20));
  __bf16* attnb = (__bf16*)(ws + ((size_t)32 << 20));
  __bf16* h2b   = (__bf16*)(ws + ((size_t)36 << 20));
  float*  h2f   = (float*) (ws + ((size_t)40 << 20));
  __bf16* fcb   = (__bf16*)(ws + ((size_t)48 << 20));
  __bf16* Wt_attn = (__bf16*)(ws + ((size_t)48 << 20));  // aliases fcb[0:6MB)
  __bf16* Wt_proj = (__bf16*)(ws + ((size_t)54 << 20));  // aliases fcb[6:8MB)
  __bf16* Wt_fc   = (__bf16*)(ws + ((size_t)4  << 20));  // aliases qkv[0:8MB)
  __bf16* Wt_mp   = (__bf16*)(ws + ((size_t)12 << 20));  // aliases qkv[8:16MB)
  float*  mp_part = (float*) (ws + ((size_t)20 << 20));  // 16MB partials

  // weights needed before attn
  wtrans_kernel<<<dim3((3 * Dm) / 32, Dm / 32), 256, 0, stream>>>(
      W_attn, Wt_attn, Dm, 3 * Dm);
  wtrans_kernel<<<dim3(Dm / 32, Dm / 32), 256, 0, stream>>>(
      W_proj, Wt_proj, Dm, Dm);

  ln_kernel<false, float><<<Bsz, 256, 0, stream>>>(
      x, nullptr, ln1_g, ln1_b, h1, nullptr);
  gemm_kernel<128, 128, false, false, true, false>
      <<<dim3(Bsz / 128, (3 * Dm) / 128), 256, 0, stream>>>(
      h1, Wt_attn, b_attn, nullptr, qkv, Bsz, 3 * Dm, Dm);
  attn_kernel<<<Bsz * Hh / 4, 256, 0, stream>>>(qkv, s_in, z_in, w1, w2, w3, w4,
                                                out_s, out_z, headp);

  // qkv is dead now: stage fc/mp weights into its region
  wtrans_kernel<<<dim3((4 * Dm) / 32, Dm / 32), 256, 0, stream>>>(
      W_fc, Wt_fc, Dm, 4 * Dm);
  wtrans_kernel<<<dim3(Dm / 32, (4 * Dm) / 32), 256, 0, stream>>>(
      W_mp, Wt_mp, 4 * Dm, Dm);

  gemm_kernel<64, 64, false, false, false, false>
      <<<dim3(Bsz / 64, Dm / 64), 256, 0, stream>>>(
      headp, Wt_proj, b_proj, nullptr, attnb, Bsz, Dm, Dm);
  ln_kernel<true, __bf16><<<Bsz, 256, 0, stream>>>(
      attnb, x, ln2_g, ln2_b, h2b, h2f);
  gemm_kernel<128, 128, true, false, false, false>
      <<<dim3(Bsz / 128, (4 * Dm) / 128), 256, 0, stream>>>(
      h2b, Wt_fc, b_fc, nullptr, fcb, Bsz, 4 * Dm, Dm);
  gemm_kernel<128, 64, false, false, true, true>
      <<<dim3(Bsz / 128, Dm / 64, 2), 256, 0, stream>>>(
      fcb, Wt_mp, nullptr, nullptr, mp_part, Bsz, Dm, 4 * Dm);
  reduce_mp_kernel<<<(Bsz * Dm) / (256 * 4), 256, 0, stream>>>(
      mp_part, b_mp, h2f, out0);
}

// Round 5
// 678.323 us; speedup vs baseline: 1.0147x; 1.0147x over previous
//
#include <hip/hip_runtime.h>
#include <hip/hip_bf16.h>
#include <math.h>

// linearGPT2 cell: B=2048 D=1024 H=16 DH=64 R=32. fp32 I/O, bf16 MFMA compute.
// Pipeline: wtrans(W fp32 -> W^T bf16) -> LN1 -> GEMM(qkv) -> attn core
//           -> GEMM(proj) -> LN2(+x) -> GEMM(fc)+GELU -> GEMM(mp,split-K=2)
//           -> reduce(+bias+res) -> out.
// GEMM: T3/T4 counted-vmcnt 2-phase. Raw s_barrier (NO vmcnt(0) drain);
//       next tile's global_load_lds stays in flight across barriers;
//       per-wave s_waitcnt vmcnt(LPS) + barrier guarantees collective
//       completion of the previous stage. 2 barriers/K-step, never drain.
// Workspace EXACTLY 64 MB; transposed weights + mp partials alias dead regions.

#define Bsz 2048
#define Dm  1024
#define Hh  16
#define DHd 64
#define Rr  32

typedef __bf16 bf16x8 __attribute__((ext_vector_type(8)));
typedef __bf16 bf16x4 __attribute__((ext_vector_type(4)));
typedef float  f32x4  __attribute__((ext_vector_type(4)));

__device__ __forceinline__ __bf16 f2bf(float x) { return (__bf16)x; }

// async global->LDS, 16B per lane, LDS dst = wave-uniform base + lane*16
#define GLOAD_LDS16(g, l) __builtin_amdgcn_global_load_lds(               \
    (const __attribute__((address_space(1))) void*)(g),                   \
    (__attribute__((address_space(3))) void*)(l), 16, 0, 0)

// ---------------- weight transpose + convert: W[K][N] f32 -> Wt[N][K] bf16 --
__global__ __launch_bounds__(256) void wtrans_kernel(
    const float* __restrict__ W, __bf16* __restrict__ Wt, int K, int N)
{
  __shared__ float tile[32][33];
  const int tx = threadIdx.x & 31;
  const int ty0 = threadIdx.x >> 5;      // 0..7
  const int bn = blockIdx.x * 32;
  const int bk = blockIdx.y * 32;
#pragma unroll
  for (int j = 0; j < 4; ++j)
    tile[ty0 + j * 8][tx] = W[(size_t)(bk + ty0 + j * 8) * N + bn + tx];
  __syncthreads();
#pragma unroll
  for (int j = 0; j < 4; ++j) {
    const int ny = ty0 + j * 8;
    Wt[(size_t)(bn + ny) * K + bk + tx] = f2bf(tile[tx][ny]);
  }
}

// ---------------- LayerNorm (optionally fused residual add + fp32 copy) ----
template<bool ADD, typename TA>
__global__ __launch_bounds__(256) void ln_kernel(
    const TA* __restrict__ a, const float* __restrict__ b2,
    const float* __restrict__ g, const float* __restrict__ beta,
    __bf16* __restrict__ outb, float* __restrict__ outf)
{
  const int row = blockIdx.x;
  const int t = threadIdx.x;
  const size_t base = (size_t)row * Dm;
  float vals[4];
#pragma unroll
  for (int i = 0; i < 4; ++i) {
    const int c = t * 4 + i;
    float v = (float)a[base + c];
    if (ADD) v += b2[base + c];
    vals[i] = v;
  }
  float sm = 0.f, sq = 0.f;
#pragma unroll
  for (int i = 0; i < 4; ++i) { sm += vals[i]; sq += vals[i] * vals[i]; }
  for (int off = 32; off > 0; off >>= 1) {
    sm += __shfl_down(sm, off);
    sq += __shfl_down(sq, off);
  }
  __shared__ float smw[4], sqw[4];
  if ((t & 63) == 0) { smw[t >> 6] = sm; sqw[t >> 6] = sq; }
  __syncthreads();
  const float S  = smw[0] + smw[1] + smw[2] + smw[3];
  const float SS = sqw[0] + sqw[1] + sqw[2] + sqw[3];
  const float mean = S * (1.f / Dm);
  const float var  = SS * (1.f / Dm) - mean * mean;
  const float inv  = rsqrtf(var + 1e-3f);
#pragma unroll
  for (int i = 0; i < 4; ++i) {
    const int c = t * 4 + i;
    const float r = g[c] * ((vals[i] - mean) * inv) + beta[c];
    outb[base + c] = f2bf(r);
    if (ADD) outf[base + c] = r;  // fp32 copy for the final residual
  }
}

// ---------------- bf16 MFMA GEMM: C = A[MxK] @ Wt[NxK]^T + bias ------------
// 256 threads = 4 waves (2x2). Wave tile (BM/2)x(BN/2). BK=32, 2-phase dbuf
// with counted vmcnt (T4): stage(t+2) issued each step, wait vmcnt(LPS)
// keeps it in flight while guaranteeing stage(t+1) landed. No vmcnt(0) drain.
// SPLITK2: blockIdx.z selects K-half; writes raw fp32 partial at Cv + z*M*N.
template<int BM, int BN, bool GELU, bool RES, bool OUTF32, bool SPLITK2>
__global__ __launch_bounds__(256) void gemm_kernel(
    const __bf16* __restrict__ A, const __bf16* __restrict__ Bt,
    const float* __restrict__ bias, const float* __restrict__ res,
    void* __restrict__ Cv, int M, int N, int K)
{
  constexpr int FM = BM / 32;   // m-frags per wave
  constexpr int FN = BN / 32;   // n-frags per wave
  constexpr int LPS = BM / 64 + BN / 64;  // gload_lds per wave per stage
  __shared__ __align__(16) __bf16 lsA[2][BM * 32];
  __shared__ __align__(16) __bf16 lsB[2][BN * 32];
  const int t = threadIdx.x;
  const int wave = t >> 6, lane = t & 63;
  const int quad = lane >> 4, l16 = lane & 15;
  const int wm = wave >> 1, wn = wave & 1;
  const int bm = blockIdx.x * BM, bn = blockIdx.y * BN;
  const int kHalf = SPLITK2 ? K / 2 : K;
  const int k0 = SPLITK2 ? blockIdx.z * kHalf : 0;
  const int nt = kHalf / 32;

  const int srow = lane >> 2, scol = (lane & 3) * 8;  // lane -> 16B in 16x32 slab
  const __bf16* Ag = A  + (size_t)(bm + wave * 16 + srow) * K + scol;
  const __bf16* Bg = Bt + (size_t)(bn + wave * 16 + srow) * K + scol;

  f32x4 acc[FM][FN];
#pragma unroll
  for (int mi = 0; mi < FM; ++mi)
#pragma unroll
    for (int ni = 0; ni < FN; ++ni)
      acc[mi][ni] = (f32x4){0.f, 0.f, 0.f, 0.f};

  auto STAGE = [&](int buf, int kt) {
#pragma unroll
    for (int i = 0; i < BM / 64; ++i)
      GLOAD_LDS16(Ag + (size_t)(i * 64) * K + kt,
                  &lsA[buf][(i * 64 + wave * 16) * 32]);
#pragma unroll
    for (int i = 0; i < BN / 64; ++i)
      GLOAD_LDS16(Bg + (size_t)(i * 64) * K + kt,
                  &lsB[buf][(i * 64 + wave * 16) * 32]);
  };
  auto COMPUTE = [&](int buf) {
    bf16x8 af[FM], bfr[FN];
#pragma unroll
    for (int mi = 0; mi < FM; ++mi)
      af[mi] = *(const bf16x8*)
          &lsA[buf][(wm * (BM / 2) + mi * 16 + l16) * 32 + quad * 8];
#pragma unroll
    for (int ni = 0; ni < FN; ++ni)
      bfr[ni] = *(const bf16x8*)
          &lsB[buf][(wn * (BN / 2) + ni * 16 + l16) * 32 + quad * 8];
#pragma unroll
    for (int mi = 0; mi < FM; ++mi)
#pragma unroll
      for (int ni = 0; ni < FN; ++ni)
        acc[mi][ni] = __builtin_amdgcn_mfma_f32_16x16x32_bf16(
            af[mi], bfr[ni], acc[mi][ni], 0, 0, 0);
  };

  // prologue: tiles 0 and 1 in flight; wait own stage0, collective barrier.
  STAGE(0, k0);
  STAGE(1, k0 + 32);
  asm volatile("s_waitcnt vmcnt(%0)" :: "i"(LPS) : "memory");
  __builtin_amdgcn_sched_barrier(0);
  __builtin_amdgcn_s_barrier();

  for (int tt = 0; tt < nt; ++tt) {
    const int buf = tt & 1;
    COMPUTE(buf);                       // lgkm waits precede MFMA use
    __builtin_amdgcn_sched_barrier(0);
    __builtin_amdgcn_s_barrier();       // all waves done consuming buf
    const int knext = k0 + 32 * (tt + 2 < nt ? tt + 2 : nt - 1);  // dummy ok
    STAGE(buf, knext);                  // overwrite now-safe; LPS more in flight
    asm volatile("s_waitcnt vmcnt(%0)" :: "i"(LPS) : "memory");  // stage(t+1) done
    __builtin_amdgcn_sched_barrier(0);
    __builtin_amdgcn_s_barrier();       // collectively: buf(t+1) ready
  }

#pragma unroll
  for (int mi = 0; mi < FM; ++mi) {
    const int row0 = bm + wm * (BM / 2) + mi * 16 + quad * 4;
#pragma unroll
    for (int ni = 0; ni < FN; ++ni) {
      const int col = bn + wn * (BN / 2) + ni * 16 + l16;
      const float bv = SPLITK2 ? 0.f : bias[col];
#pragma unroll
      for (int i = 0; i < 4; ++i) {
        const int row = row0 + i;
        float v = acc[mi][ni][i] + bv;
        if (SPLITK2) {
          ((float*)Cv)[(size_t)blockIdx.z * M * N + (size_t)row * N + col] = v;
        } else {
          if (GELU) v = 0.5f * v * (1.0f + erff(v * 0.70710678118654752f));
          if (RES) v += res[(size_t)row * N + col];
          if (OUTF32) ((float*)Cv)[(size_t)row * N + col] = v;
          else        ((__bf16*)Cv)[(size_t)row * N + col] = f2bf(v);
        }
      }
    }
  }
}

// ---------------- split-K reduce: out = p0 + p1 + bias + res ---------------
__global__ __launch_bounds__(256) void reduce_mp_kernel(
    const float* __restrict__ p, const float* __restrict__ bias,
    const float* __restrict__ res, float* __restrict__ out)
{
  const size_t i = ((size_t)blockIdx.x * 256 + threadIdx.x) * 4;
  const f32x4 a = *(const f32x4*)(p + i);
  const f32x4 b = *(const f32x4*)(p + (size_t)Bsz * Dm + i);
  const f32x4 r = *(const f32x4*)(res + i);
  const f32x4 bv = *(const f32x4*)(bias + (i & (Dm - 1)));
  *(f32x4*)(out + i) = a + b + r + bv;
}

// ---------------- fused linear-attention core ------------------------------
// 256 threads = 4 waves, one (b,h) per wave. phi sigmoids, new_s/new_z,
// head=num/den. s/new_s stream vectorized to f32x4 (16B/lane).
__global__ __launch_bounds__(256) void attn_kernel(
    const float* __restrict__ qkv, const float* __restrict__ s,
    const float* __restrict__ z,
    const float* __restrict__ w1, const float* __restrict__ w2,
    const float* __restrict__ w3, const float* __restrict__ w4,
    float* __restrict__ new_s, float* __restrict__ new_z,
    __bf16* __restrict__ head)
{
  const int wave = threadIdx.x >> 6, lane = threadIdx.x & 63;
  const int bh = blockIdx.x * 4 + wave;
  const int b = bh >> 4, h = bh & 15;
  __shared__ float ksh[4][64], qsh[4][64], vsh[4][64];
  __shared__ float phish[4][4][32];
  __shared__ float nzsh[4][32];

  const float* qrow = qkv + (size_t)b * (3 * Dm) + h * 64 + lane;
  qsh[wave][lane] = qrow[0];
  ksh[wave][lane] = qrow[Dm];
  vsh[wave][lane] = qrow[2 * Dm];
  __syncthreads();

  {  // 128 dots of length 64: 2 per thread. w[h,d,r] stride 32 over d.
    const int r = lane & 31;
    for (int it = 0; it < 2; ++it) {
      const int mm = (lane >> 5) + it * 2;            // 0/1 then 2/3
      const float* wp = (mm == 0) ? w1 : (mm == 1) ? w2 : (mm == 2) ? w3 : w4;
      const float* w = wp + (size_t)h * (DHd * Rr) + r;
      const float* src = (it == 0) ? ksh[wave] : qsh[wave];
      float acc = 0.f;
#pragma unroll 8
      for (int d = 0; d < 64; ++d) acc += src[d] * w[(size_t)d * 32];
      phish[wave][mm][r] = 1.f / (1.f + expf(-acc));
    }
  }
  __syncthreads();

  const size_t zbase = (size_t)b * (Rr * Hh) + h * Rr;
  if (lane < 32) {
    const float nz = z[zbase + lane] + phish[wave][1][lane];
    new_z[zbase + lane] = nz;
    nzsh[wave][lane] = nz;
  }
  __syncthreads();

  float den = 0.f;
#pragma unroll
  for (int r = 0; r < 32; ++r) den += phish[wave][3][r] * nzsh[wave][r];

  const size_t sbase = ((size_t)b * Hh + h) * (Rr * DHd);
  const int d4 = (lane & 15) * 4, rr = lane >> 4;
  const f32x4 vv4 = *(const f32x4*)&vsh[wave][d4];
  f32x4 num4 = {0.f, 0.f, 0.f, 0.f};
#pragma unroll
  for (int rb = 0; rb < 8; ++rb) {
    const int r = rb * 4 + rr;
    f32x4 sv = *(const f32x4*)(s + sbase + r * 64 + d4);
    const f32x4 ns = sv + phish[wave][0][r] * vv4;
    *(f32x4*)(new_s + sbase + r * 64 + d4) = ns;
    num4 += phish[wave][2][r] * ns;
  }
#pragma unroll
  for (int i = 0; i < 4; ++i) {
    num4[i] += __shfl_xor(num4[i], 16);
    num4[i] += __shfl_xor(num4[i], 32);
  }
  if (rr == 0) {
    const float inv = 1.f / den;
    bf16x4 hv;
#pragma unroll
    for (int i = 0; i < 4; ++i) hv[i] = f2bf(num4[i] * inv);
    *(bf16x4*)(head + (size_t)b * Dm + h * 64 + d4) = hv;
  }
}

// ---------------------------------------------------------------------------
extern "C" void kernel_launch(void* const* d_in, const int* in_sizes, int n_in,
                              void* d_out, int out_size, void* d_ws, size_t ws_size,
                              hipStream_t stream)
{
  const float* x      = (const float*)d_in[0];
  const float* s_in   = (const float*)d_in[1];
  const float* z_in   = (const float*)d_in[2];
  const float* ln1_g  = (const float*)d_in[3];
  const float* ln1_b  = (const float*)d_in[4];
  const float* ln2_g  = (const float*)d_in[5];
  const float* ln2_b  = (const float*)d_in[6];
  const float* W_attn = (const float*)d_in[7];
  const float* b_attn = (const float*)d_in[8];
  const float* W_proj = (const float*)d_in[9];
  const float* b_proj = (const float*)d_in[10];
  const float* W_fc   = (const float*)d_in[11];
  const float* b_fc   = (const float*)d_in[12];
  const float* W_mp   = (const float*)d_in[13];
  const float* b_mp   = (const float*)d_in[14];
  const float* w1     = (const float*)d_in[15];
  const float* w2     = (const float*)d_in[16];
  const float* w3     = (const float*)d_in[17];
  const float* w4     = (const float*)d_in[18];

  float* out0  = (float*)d_out;                        // [B,D]
  float* out_s = out0 + (size_t)Bsz * Dm;              // [B,D*R]
  float* out_z = out_s + (size_t)Bsz * Dm * Rr;        // [B,R*H]

  // 64 MB workspace layout (offsets in MB):
  //   0: h1(4) | 4: qkv(24) | 28: headp(4) | 32: attnb(4) | 36: h2b(4)
  //  40: h2f(8) | 48: fcb(16)
  // aliases: Wt_attn@48(6) Wt_proj@54(2)  [dead before fcb written]
  //          Wt_fc@4(8)    Wt_mp@12(8)    [written after qkv's last read]
  //          mp_part@20(16)               [qkv tail + headp + attnb, all dead]
  char* ws = (char*)d_ws;
  __bf16* h1    = (__bf16*)(ws);
  float*  qkv   = (float*) (ws + ((size_t)4  << 20));
  __bf16* headp = (__bf16*)(ws + ((size_t)28 << 20));
  __bf16* attnb = (__bf16*)(ws + ((size_t)32 << 20));
  __bf16* h2b   = (__bf16*)(ws + ((size_t)36 << 20));
  float*  h2f   = (float*) (ws + ((size_t)40 << 20));
  __bf16* fcb   = (__bf16*)(ws + ((size_t)48 << 20));
  __bf16* Wt_attn = (__bf16*)(ws + ((size_t)48 << 20));  // aliases fcb[0:6MB)
  __bf16* Wt_proj = (__bf16*)(ws + ((size_t)54 << 20));  // aliases fcb[6:8MB)
  __bf16* Wt_fc   = (__bf16*)(ws + ((size_t)4  << 20));  // aliases qkv[0:8MB)
  __bf16* Wt_mp   = (__bf16*)(ws + ((size_t)12 << 20));  // aliases qkv[8:16MB)
  float*  mp_part = (float*) (ws + ((size_t)20 << 20));  // 16MB partials

  // weights needed before attn
  wtrans_kernel<<<dim3((3 * Dm) / 32, Dm / 32), 256, 0, stream>>>(
      W_attn, Wt_attn, Dm, 3 * Dm);
  wtrans_kernel<<<dim3(Dm / 32, Dm / 32), 256, 0, stream>>>(
      W_proj, Wt_proj, Dm, Dm);

  ln_kernel<false, float><<<Bsz, 256, 0, stream>>>(
      x, nullptr, ln1_g, ln1_b, h1, nullptr);
  gemm_kernel<128, 128, false, false, true, false>
      <<<dim3(Bsz / 128, (3 * Dm) / 128), 256, 0, stream>>>(
      h1, Wt_attn, b_attn, nullptr, qkv, Bsz, 3 * Dm, Dm);
  attn_kernel<<<Bsz * Hh / 4, 256, 0, stream>>>(qkv, s_in, z_in, w1, w2, w3, w4,
                                                out_s, out_z, headp);

  // qkv is dead now: stage fc/mp weights into its region
  wtrans_kernel<<<dim3((4 * Dm) / 32, Dm / 32), 256, 0, stream>>>(
      W_fc, Wt_fc, Dm, 4 * Dm);
  wtrans_kernel<<<dim3(Dm / 32, (4 * Dm) / 32), 256, 0, stream>>>(
      W_mp, Wt_mp, 4 * Dm, Dm);

  gemm_kernel<64, 64, false, false, false, false>
      <<<dim3(Bsz / 64, Dm / 64), 256, 0, stream>>>(
      headp, Wt_proj, b_proj, nullptr, attnb, Bsz, Dm, Dm);
  ln_kernel<true, __bf16><<<Bsz, 256, 0, stream>>>(
      attnb, x, ln2_g, ln2_b, h2b, h2f);
  gemm_kernel<128, 128, true, false, false, false>
      <<<dim3(Bsz / 128, (4 * Dm) / 128), 256, 0, stream>>>(
      h2b, Wt_fc, b_fc, nullptr, fcb, Bsz, 4 * Dm, Dm);
  gemm_kernel<128, 64, false, false, true, true>
      <<<dim3(Bsz / 128, Dm / 64, 2), 256, 0, stream>>>(
      fcb, Wt_mp, nullptr, nullptr, mp_part, Bsz, Dm, 4 * Dm);
  reduce_mp_kernel<<<(Bsz * Dm) / (256 * 4), 256, 0, stream>>>(
      mp_part, b_mp, h2f, out0);
}

// Round 6
// 664.163 us; speedup vs baseline: 1.0363x; 1.0213x over previous
//
#include <hip/hip_runtime.h>
#include <hip/hip_bf16.h>
#include <math.h>

// linearGPT2 cell: B=2048 D=1024 H=16 DH=64 R=32. fp32 I/O, bf16 MFMA compute.
// Pipeline: wtrans(W fp32 -> W^T bf16) -> LN1 -> GEMM(qkv) -> attn core
//           -> GEMM(proj) -> LN2(+x) -> GEMM(fc)+GELU -> GEMM(mp,split-K=2)
//           -> reduce(+bias+res) -> out.
// GEMM: counted-vmcnt 2-phase dbuf (T4) + XCD-aware block swizzle (T1).
// Attn: one head/block; w1..w4[h] staged to LDS (conflict-free [65] pad);
//       phi reads LDS not strided-global (kills 1GB of latency-exposed L2 reads).
// Workspace EXACTLY 64 MB; transposed weights + mp partials alias dead regions.

#define Bsz 2048
#define Dm  1024
#define Hh  16
#define DHd 64
#define Rr  32

typedef __bf16 bf16x8 __attribute__((ext_vector_type(8)));
typedef __bf16 bf16x4 __attribute__((ext_vector_type(4)));
typedef float  f32x4  __attribute__((ext_vector_type(4)));

__device__ __forceinline__ __bf16 f2bf(float x) { return (__bf16)x; }

// async global->LDS, 16B per lane, LDS dst = wave-uniform base + lane*16
#define GLOAD_LDS16(g, l) __builtin_amdgcn_global_load_lds(               \
    (const __attribute__((address_space(1))) void*)(g),                   \
    (__attribute__((address_space(3))) void*)(l), 16, 0, 0)

// ---------------- weight transpose + convert: W[K][N] f32 -> Wt[N][K] bf16 --
__global__ __launch_bounds__(256) void wtrans_kernel(
    const float* __restrict__ W, __bf16* __restrict__ Wt, int K, int N)
{
  __shared__ float tile[32][33];
  const int tx = threadIdx.x & 31;
  const int ty0 = threadIdx.x >> 5;      // 0..7
  const int bn = blockIdx.x * 32;
  const int bk = blockIdx.y * 32;
#pragma unroll
  for (int j = 0; j < 4; ++j)
    tile[ty0 + j * 8][tx] = W[(size_t)(bk + ty0 + j * 8) * N + bn + tx];
  __syncthreads();
#pragma unroll
  for (int j = 0; j < 4; ++j) {
    const int ny = ty0 + j * 8;
    Wt[(size_t)(bn + ny) * K + bk + tx] = f2bf(tile[tx][ny]);
  }
}

// ---------------- LayerNorm (optionally fused residual add + fp32 copy) ----
template<bool ADD, typename TA>
__global__ __launch_bounds__(256) void ln_kernel(
    const TA* __restrict__ a, const float* __restrict__ b2,
    const float* __restrict__ g, const float* __restrict__ beta,
    __bf16* __restrict__ outb, float* __restrict__ outf)
{
  const int row = blockIdx.x;
  const int t = threadIdx.x;
  const size_t base = (size_t)row * Dm;
  float vals[4];
#pragma unroll
  for (int i = 0; i < 4; ++i) {
    const int c = t * 4 + i;
    float v = (float)a[base + c];
    if (ADD) v += b2[base + c];
    vals[i] = v;
  }
  float sm = 0.f, sq = 0.f;
#pragma unroll
  for (int i = 0; i < 4; ++i) { sm += vals[i]; sq += vals[i] * vals[i]; }
  for (int off = 32; off > 0; off >>= 1) {
    sm += __shfl_down(sm, off);
    sq += __shfl_down(sq, off);
  }
  __shared__ float smw[4], sqw[4];
  if ((t & 63) == 0) { smw[t >> 6] = sm; sqw[t >> 6] = sq; }
  __syncthreads();
  const float S  = smw[0] + smw[1] + smw[2] + smw[3];
  const float SS = sqw[0] + sqw[1] + sqw[2] + sqw[3];
  const float mean = S * (1.f / Dm);
  const float var  = SS * (1.f / Dm) - mean * mean;
  const float inv  = rsqrtf(var + 1e-3f);
#pragma unroll
  for (int i = 0; i < 4; ++i) {
    const int c = t * 4 + i;
    const float r = g[c] * ((vals[i] - mean) * inv) + beta[c];
    outb[base + c] = f2bf(r);
    if (ADD) outf[base + c] = r;  // fp32 copy for the final residual
  }
}

// ---------------- bf16 MFMA GEMM: C = A[MxK] @ Wt[NxK]^T + bias ------------
// 256 threads = 4 waves (2x2). Wave tile (BM/2)x(BN/2). BK=32, 2-phase dbuf
// with counted vmcnt (T4). XCD-aware swizzle (T1): each XCD gets a contiguous
// chunk of the (by-major) grid so same-N-panel blocks share an L2.
// SPLITK2: blockIdx.z selects K-half; writes raw fp32 partial at Cv + z*M*N.
template<int BM, int BN, bool GELU, bool RES, bool OUTF32, bool SPLITK2>
__global__ __launch_bounds__(256) void gemm_kernel(
    const __bf16* __restrict__ A, const __bf16* __restrict__ Bt,
    const float* __restrict__ bias, const float* __restrict__ res,
    void* __restrict__ Cv, int M, int N, int K)
{
  constexpr int FM = BM / 32;   // m-frags per wave
  constexpr int FN = BN / 32;   // n-frags per wave
  constexpr int LPS = BM / 64 + BN / 64;  // gload_lds per wave per stage
  __shared__ __align__(16) __bf16 lsA[2][BM * 32];
  __shared__ __align__(16) __bf16 lsB[2][BN * 32];
  const int t = threadIdx.x;
  const int wave = t >> 6, lane = t & 63;
  const int quad = lane >> 4, l16 = lane & 15;
  const int wm = wave >> 1, wn = wave & 1;

  // T1 bijective XCD swizzle (all grids are multiples of 8 blocks)
  int wg = blockIdx.y * gridDim.x + blockIdx.x;
  const int nwg = gridDim.x * gridDim.y;
  const int cpx = nwg >> 3;
  wg = (wg & 7) * cpx + (wg >> 3);
  const int bm = (wg % gridDim.x) * BM, bn = (wg / gridDim.x) * BN;

  const int kHalf = SPLITK2 ? K / 2 : K;
  const int k0 = SPLITK2 ? blockIdx.z * kHalf : 0;
  const int nt = kHalf / 32;

  const int srow = lane >> 2, scol = (lane & 3) * 8;  // lane -> 16B in 16x32 slab
  const __bf16* Ag = A  + (size_t)(bm + wave * 16 + srow) * K + scol;
  const __bf16* Bg = Bt + (size_t)(bn + wave * 16 + srow) * K + scol;

  f32x4 acc[FM][FN];
#pragma unroll
  for (int mi = 0; mi < FM; ++mi)
#pragma unroll
    for (int ni = 0; ni < FN; ++ni)
      acc[mi][ni] = (f32x4){0.f, 0.f, 0.f, 0.f};

  auto STAGE = [&](int buf, int kt) {
#pragma unroll
    for (int i = 0; i < BM / 64; ++i)
      GLOAD_LDS16(Ag + (size_t)(i * 64) * K + kt,
                  &lsA[buf][(i * 64 + wave * 16) * 32]);
#pragma unroll
    for (int i = 0; i < BN / 64; ++i)
      GLOAD_LDS16(Bg + (size_t)(i * 64) * K + kt,
                  &lsB[buf][(i * 64 + wave * 16) * 32]);
  };
  auto COMPUTE = [&](int buf) {
    bf16x8 af[FM], bfr[FN];
#pragma unroll
    for (int mi = 0; mi < FM; ++mi)
      af[mi] = *(const bf16x8*)
          &lsA[buf][(wm * (BM / 2) + mi * 16 + l16) * 32 + quad * 8];
#pragma unroll
    for (int ni = 0; ni < FN; ++ni)
      bfr[ni] = *(const bf16x8*)
          &lsB[buf][(wn * (BN / 2) + ni * 16 + l16) * 32 + quad * 8];
#pragma unroll
    for (int mi = 0; mi < FM; ++mi)
#pragma unroll
      for (int ni = 0; ni < FN; ++ni)
        acc[mi][ni] = __builtin_amdgcn_mfma_f32_16x16x32_bf16(
            af[mi], bfr[ni], acc[mi][ni], 0, 0, 0);
  };

  // prologue: tiles 0 and 1 in flight; wait own stage0, collective barrier.
  STAGE(0, k0);
  STAGE(1, k0 + 32);
  asm volatile("s_waitcnt vmcnt(%0)" :: "i"(LPS) : "memory");
  __builtin_amdgcn_sched_barrier(0);
  __builtin_amdgcn_s_barrier();

  for (int tt = 0; tt < nt; ++tt) {
    const int buf = tt & 1;
    COMPUTE(buf);                       // lgkm waits precede MFMA use
    __builtin_amdgcn_sched_barrier(0);
    __builtin_amdgcn_s_barrier();       // all waves done consuming buf
    const int knext = k0 + 32 * (tt + 2 < nt ? tt + 2 : nt - 1);  // dummy ok
    STAGE(buf, knext);                  // overwrite now-safe; LPS more in flight
    asm volatile("s_waitcnt vmcnt(%0)" :: "i"(LPS) : "memory");  // stage(t+1) done
    __builtin_amdgcn_sched_barrier(0);
    __builtin_amdgcn_s_barrier();       // collectively: buf(t+1) ready
  }

#pragma unroll
  for (int mi = 0; mi < FM; ++mi) {
    const int row0 = bm + wm * (BM / 2) + mi * 16 + quad * 4;
#pragma unroll
    for (int ni = 0; ni < FN; ++ni) {
      const int col = bn + wn * (BN / 2) + ni * 16 + l16;
      const float bv = SPLITK2 ? 0.f : bias[col];
#pragma unroll
      for (int i = 0; i < 4; ++i) {
        const int row = row0 + i;
        float v = acc[mi][ni][i] + bv;
        if (SPLITK2) {
          ((float*)Cv)[(size_t)blockIdx.z * M * N + (size_t)row * N + col] = v;
        } else {
          if (GELU) v = 0.5f * v * (1.0f + erff(v * 0.70710678118654752f));
          if (RES) v += res[(size_t)row * N + col];
          if (OUTF32) ((float*)Cv)[(size_t)row * N + col] = v;
          else        ((__bf16*)Cv)[(size_t)row * N + col] = f2bf(v);
        }
      }
    }
  }
}

// ---------------- split-K reduce: out = p0 + p1 + bias + res ---------------
__global__ __launch_bounds__(256) void reduce_mp_kernel(
    const float* __restrict__ p, const float* __restrict__ bias,
    const float* __restrict__ res, float* __restrict__ out)
{
  const size_t i = ((size_t)blockIdx.x * 256 + threadIdx.x) * 4;
  const f32x4 a = *(const f32x4*)(p + i);
  const f32x4 b = *(const f32x4*)(p + (size_t)Bsz * Dm + i);
  const f32x4 r = *(const f32x4*)(res + i);
  const f32x4 bv = *(const f32x4*)(bias + (i & (Dm - 1)));
  *(f32x4*)(out + i) = a + b + r + bv;
}

// ---------------- fused linear-attention core ------------------------------
// One head per block, 4 batch rows (one per wave). w1..w4[h] (4x 64x32 fp32)
// staged to LDS as wl[mm][r][d] with [65] pad: phi LDS reads are bank-conflict
// free ((r+d)%32 distinct across lanes). s/new_s stream f32x4 (16B/lane).
__global__ __launch_bounds__(256) void attn_kernel(
    const float* __restrict__ qkv, const float* __restrict__ s,
    const float* __restrict__ z,
    const float* __restrict__ w1, const float* __restrict__ w2,
    const float* __restrict__ w3, const float* __restrict__ w4,
    float* __restrict__ new_s, float* __restrict__ new_z,
    __bf16* __restrict__ head)
{
  const int wave = threadIdx.x >> 6, lane = threadIdx.x & 63;
  const int h = blockIdx.x & 15;
  const int b = (blockIdx.x >> 4) * 4 + wave;
  __shared__ float wl[4][Rr][65];       // [mm][r][d], pad 65 vs d=0..63
  __shared__ float ksh[4][64], qsh[4][64], vsh[4][64];
  __shared__ float phish[4][4][32];
  __shared__ float nzsh[4][32];

  {  // stage w[wave] (wave mm handles w_{mm+1}): 2048 floats, 8 f32x4/lane
    const float* wp = (wave == 0) ? w1 : (wave == 1) ? w2 : (wave == 2) ? w3 : w4;
    const float* wh = wp + (size_t)h * (DHd * Rr);
#pragma unroll
    for (int j = 0; j < 8; ++j) {
      const int e = lane * 4 + j * 256;         // e%32 in {0,4,...,28}
      const f32x4 v = *(const f32x4*)(wh + e);
      const int d = e >> 5, r0 = e & 31;
#pragma unroll
      for (int q = 0; q < 4; ++q) wl[wave][r0 + q][d] = v[q];
    }
  }
  const float* qrow = qkv + (size_t)b * (3 * Dm) + h * 64 + lane;
  qsh[wave][lane] = qrow[0];
  ksh[wave][lane] = qrow[Dm];
  vsh[wave][lane] = qrow[2 * Dm];
  __syncthreads();

  {  // 128 dots of length 64 per wave: 2 per thread, all operands in LDS
    const int r = lane & 31;
    const int half = lane >> 5;
    for (int it = 0; it < 2; ++it) {
      const int mm = half + it * 2;             // 0/1 then 2/3
      const float* wr = &wl[mm][r][0];
      const float* src = (it == 0) ? ksh[wave] : qsh[wave];
      float acc = 0.f;
#pragma unroll 8
      for (int d = 0; d < 64; ++d) acc += src[d] * wr[d];
      phish[wave][mm][r] = 1.f / (1.f + expf(-acc));
    }
  }
  __syncthreads();

  const size_t zbase = (size_t)b * (Rr * Hh) + h * Rr;
  if (lane < 32) {
    const float nz = z[zbase + lane] + phish[wave][1][lane];
    new_z[zbase + lane] = nz;
    nzsh[wave][lane] = nz;
  }
  __syncthreads();

  float den = 0.f;
#pragma unroll
  for (int r = 0; r < 32; ++r) den += phish[wave][3][r] * nzsh[wave][r];

  const size_t sbase = ((size_t)b * Hh + h) * (Rr * DHd);
  const int d4 = (lane & 15) * 4, rr = lane >> 4;
  const f32x4 vv4 = *(const f32x4*)&vsh[wave][d4];
  f32x4 num4 = {0.f, 0.f, 0.f, 0.f};
#pragma unroll
  for (int rb = 0; rb < 8; ++rb) {
    const int r = rb * 4 + rr;
    f32x4 sv = *(const f32x4*)(s + sbase + r * 64 + d4);
    const f32x4 ns = sv + phish[wave][0][r] * vv4;
    *(f32x4*)(new_s + sbase + r * 64 + d4) = ns;
    num4 += phish[wave][2][r] * ns;
  }
#pragma unroll
  for (int i = 0; i < 4; ++i) {
    num4[i] += __shfl_xor(num4[i], 16);
    num4[i] += __shfl_xor(num4[i], 32);
  }
  if (rr == 0) {
    const float inv = 1.f / den;
    bf16x4 hv;
#pragma unroll
    for (int i = 0; i < 4; ++i) hv[i] = f2bf(num4[i] * inv);
    *(bf16x4*)(head + (size_t)b * Dm + h * 64 + d4) = hv;
  }
}

// ---------------------------------------------------------------------------
extern "C" void kernel_launch(void* const* d_in, const int* in_sizes, int n_in,
                              void* d_out, int out_size, void* d_ws, size_t ws_size,
                              hipStream_t stream)
{
  const float* x      = (const float*)d_in[0];
  const float* s_in   = (const float*)d_in[1];
  const float* z_in   = (const float*)d_in[2];
  const float* ln1_g  = (const float*)d_in[3];
  const float* ln1_b  = (const float*)d_in[4];
  const float* ln2_g  = (const float*)d_in[5];
  const float* ln2_b  = (const float*)d_in[6];
  const float* W_attn = (const float*)d_in[7];
  const float* b_attn = (const float*)d_in[8];
  const float* W_proj = (const float*)d_in[9];
  const float* b_proj = (const float*)d_in[10];
  const float* W_fc   = (const float*)d_in[11];
  const float* b_fc   = (const float*)d_in[12];
  const float* W_mp   = (const float*)d_in[13];
  const float* b_mp   = (const float*)d_in[14];
  const float* w1     = (const float*)d_in[15];
  const float* w2     = (const float*)d_in[16];
  const float* w3     = (const float*)d_in[17];
  const float* w4     = (const float*)d_in[18];

  float* out0  = (float*)d_out;                        // [B,D]
  float* out_s = out0 + (size_t)Bsz * Dm;              // [B,D*R]
  float* out_z = out_s + (size_t)Bsz * Dm * Rr;        // [B,R*H]

  // 64 MB workspace layout (offsets in MB):
  //   0: h1(4) | 4: qkv(24) | 28: headp(4) | 32: attnb(4) | 36: h2b(4)
  //  40: h2f(8) | 48: fcb(16)
  // aliases: Wt_attn@48(6) Wt_proj@54(2)  [dead before fcb written]
  //          Wt_fc@4(8)    Wt_mp@12(8)    [written after qkv's last read]
  //          mp_part@20(16)               [qkv tail + headp + attnb, all dead]
  char* ws = (char*)d_ws;
  __bf16* h1    = (__bf16*)(ws);
  float*  qkv   = (float*) (ws + ((size_t)4  << 20));
  __bf16* headp = (__bf16*)(ws + ((size_t)28 << 20));
  __bf16* attnb = (__bf16*)(ws + ((size_t)32 << 20));
  __bf16* h2b   = (__bf16*)(ws + ((size_t)36 << 20));
  float*  h2f   = (float*) (ws + ((size_t)40 << 20));
  __bf16* fcb   = (__bf16*)(ws + ((size_t)48 << 20));
  __bf16* Wt_attn = (__bf16*)(ws + ((size_t)48 << 20));  // aliases fcb[0:6MB)
  __bf16* Wt_proj = (__bf16*)(ws + ((size_t)54 << 20));  // aliases fcb[6:8MB)
  __bf16* Wt_fc   = (__bf16*)(ws + ((size_t)4  << 20));  // aliases qkv[0:8MB)
  __bf16* Wt_mp   = (__bf16*)(ws + ((size_t)12 << 20));  // aliases qkv[8:16MB)
  float*  mp_part = (float*) (ws + ((size_t)20 << 20));  // 16MB partials

  // weights needed before attn
  wtrans_kernel<<<dim3((3 * Dm) / 32, Dm / 32), 256, 0, stream>>>(
      W_attn, Wt_attn, Dm, 3 * Dm);
  wtrans_kernel<<<dim3(Dm / 32, Dm / 32), 256, 0, stream>>>(
      W_proj, Wt_proj, Dm, Dm);

  ln_kernel<false, float><<<Bsz, 256, 0, stream>>>(
      x, nullptr, ln1_g, ln1_b, h1, nullptr);
  gemm_kernel<128, 128, false, false, true, false>
      <<<dim3(Bsz / 128, (3 * Dm) / 128), 256, 0, stream>>>(
      h1, Wt_attn, b_attn, nullptr, qkv, Bsz, 3 * Dm, Dm);
  attn_kernel<<<Bsz * Hh / 4, 256, 0, stream>>>(qkv, s_in, z_in, w1, w2, w3, w4,
                                                out_s, out_z, headp);

  // qkv is dead now: stage fc/mp weights into its region
  wtrans_kernel<<<dim3((4 * Dm) / 32, Dm / 32), 256, 0, stream>>>(
      W_fc, Wt_fc, Dm, 4 * Dm);
  wtrans_kernel<<<dim3(Dm / 32, (4 * Dm) / 32), 256, 0, stream>>>(
      W_mp, Wt_mp, 4 * Dm, Dm);

  gemm_kernel<64, 64, false, false, false, false>
      <<<dim3(Bsz / 64, Dm / 64), 256, 0, stream>>>(
      headp, Wt_proj, b_proj, nullptr, attnb, Bsz, Dm, Dm);
  ln_kernel<true, __bf16><<<Bsz, 256, 0, stream>>>(
      attnb, x, ln2_g, ln2_b, h2b, h2f);
  gemm_kernel<128, 128, true, false, false, false>
      <<<dim3(Bsz / 128, (4 * Dm) / 128), 256, 0, stream>>>(
      h2b, Wt_fc, b_fc, nullptr, fcb, Bsz, 4 * Dm, Dm);
  gemm_kernel<128, 64, false, false, true, true>
      <<<dim3(Bsz / 128, Dm / 64, 2), 256, 0, stream>>>(
      fcb, Wt_mp, nullptr, nullptr, mp_part, Bsz, Dm, 4 * Dm);
  reduce_mp_kernel<<<(Bsz * Dm) / (256 * 4), 256, 0, stream>>>(
      mp_part, b_mp, h2f, out0);
}